// Round 18
// baseline (370.104 us; speedup 1.0000x reference)
//
#include <hip/hip_runtime.h>

#define H 128
#define EF 32
#define TT 14
#define LH 32
#define KDIM 416   // 3H+EF
#define GOUT 512   // [r_pre, z_pre, i_n, h_n] each 128
#define KTOT 544   // 416 (agg) + 128 (memory)
#define KP 288     // pred GEMM K: 128 ms + 128 md + 32 h

typedef __attribute__((ext_vector_type(8))) short bf16x8;
typedef __attribute__((ext_vector_type(4))) float f32x4;

// native-HW nonlinearities: v_exp_f32 computes 2^x; v_rcp_f32 is ~1ulp.
__device__ __forceinline__ float sigmoidf_(float x) {
  float e = __builtin_amdgcn_exp2f(x * -1.442695041f);   // exp(-x)
  return __builtin_amdgcn_rcpf(1.0f + e);
}
__device__ __forceinline__ float tanhfast_(float x) {
  float e = __builtin_amdgcn_exp2f(x * 2.885390082f);    // exp(2x)
  return 1.0f - 2.0f * __builtin_amdgcn_rcpf(e + 1.0f);
}
__device__ __forceinline__ ushort f2bf(float x) {
  uint u = __float_as_uint(x);
  u += 0x7fff + ((u >> 16) & 1);   // RTNE
  return (ushort)(u >> 16);
}

// ---- FUSED: {mem->bf16 | count | WcatT | prep_pred} block-ranges + LSTM blocks ----
// Round-17 experiment: 256-thread blocks (4 waves, 64 edges per lstm block) for finer
// CU packing at identical VGPR=64. Round-16 lesson: any register increase here is an
// occupancy cliff — NONLIN must stay register-neutral.
__global__ __launch_bounds__(256) void pre_lstm_kernel(
    const float* __restrict__ gWih, const float* __restrict__ gWhh,
    ushort* __restrict__ WcatT,
    const float* __restrict__ W1, const float* __restrict__ b1,
    const float* __restrict__ static_W, const float* __restrict__ static_b,
    const float* __restrict__ price_W, const float* __restrict__ price_b,
    const float* __restrict__ party_emb, const float* __restrict__ state_emb,
    ushort* __restrict__ Wcombb, float* __restrict__ tab_p, float* __restrict__ tab_s,
    float* __restrict__ bias2,
    const float* __restrict__ mem, ushort* __restrict__ mem_b,
    const int* __restrict__ src, const int* __restrict__ dst, int* cnt,
    const float* __restrict__ price_seq,
    const float* __restrict__ lWih, const float* __restrict__ lWhh,
    const float* __restrict__ lbih, const float* __restrict__ lbhh,
    ushort* __restrict__ houtb,
    int E, int N, int nbC, int nbN, int nbB, int nbP) {
  __shared__ union {
    float ps[64][15];
    float G1s[4][32];
  } sm;
  int b = blockIdx.x;
  int tid = threadIdx.x;
  int nbPre = nbC + nbN + nbB + nbP;

  if (b < nbC) {
    int total = N * H;
    for (int i = tid + 256 * b; i < total; i += 256 * nbC) mem_b[i] = f2bf(mem[i]);
  } else if (b < nbC + nbN) {
    int cb = b - nbC;
    for (int e = tid + 256 * cb; e < E; e += 256 * nbN) {
      atomicAdd(&cnt[dst[e]], 1);
      atomicAdd(&cnt[src[e]], 1);
    }
  } else if (b < nbC + nbN + nbB) {
    int i = (b - nbC - nbN) * 256 + tid;
    if (i < GOUT * KTOT) {
      int o = i / KTOT, k = i % KTOT;
      int j = o & 127;
      float v = 0.f;
      if (o < 256) {
        int row = (o < 128) ? j : (128 + j);
        v = (k < KDIM) ? gWih[row * KDIM + k] : gWhh[row * H + (k - KDIM)];
      } else if (o < 384) {
        v = (k < KDIM) ? gWih[(256 + j) * KDIM + k] : 0.f;
      } else {
        v = (k < KDIM) ? 0.f : gWhh[(256 + j) * H + (k - KDIM)];
      }
      WcatT[i] = f2bf(v);
    }
  } else if (b < nbPre) {
    int ob = (b - nbC - nbN - nbB) * 4;
    if (tid < 128) {
      int ol = tid >> 5, k = tid & 31;
      int o = ob + ol;
      float g = 0.f, m = 0.f;
      for (int j = 0; j < 128; j++) {
        g = fmaf(W1[o * 384 + j], static_W[j * 32 + k], g);
        m = fmaf(W1[o * 384 + 128 + j] + W1[o * 384 + 256 + j], price_W[j * 32 + k], m);
      }
      sm.G1s[ol][k] = g;
      Wcombb[o * KP + 256 + k] = f2bf(m);
    }
    for (int idx = tid; idx < 1024; idx += 256) {
      int ol = idx >> 8, j = idx & 255;
      int o = ob + ol;
      Wcombb[o * KP + j] = f2bf(W1[o * 384 + j]);
    }
    __syncthreads();
    for (int idx = tid; idx < 216; idx += 256) {
      if (idx < 16) {
        int p = idx >> 2, ol = idx & 3;
        float s = 0.f;
        for (int k = 0; k < 16; k++) s = fmaf(sm.G1s[ol][k], party_emb[p * 16 + k], s);
        tab_p[p * 64 + ob + ol] = s;
      } else {
        int i2 = idx - 16;
        int si = i2 >> 2, ol = i2 & 3;
        float s = 0.f;
        for (int k = 0; k < 16; k++) s = fmaf(sm.G1s[ol][16 + k], state_emb[si * 16 + k], s);
        tab_s[si * 64 + ob + ol] = s;
      }
    }
    if (tid < 4) {
      int o = ob + tid;
      float s = b1[o];
      for (int j = 0; j < 128; j++) {
        s = fmaf(W1[o * 384 + j], static_b[j], s);
        s = fmaf(W1[o * 384 + 128 + j] + W1[o * 384 + 256 + j], price_b[j], s);
      }
      bias2[o] = s;
    }
  } else {
    // ================= LSTM path: 4 waves x 16 edges = 64 edges =================
    int lb = b - nbPre;
    int lane = tid & 63;
    int el = lane & 15;
    int g = lane >> 4;
    int wv = tid >> 6;                 // 0..3
    int row0 = lb * 64;
    int el_local = wv * 16 + el;       // 0..63
    int e = row0 + el_local;
    bool valid = (e < E);

    for (int idx = tid; idx < 64 * TT; idx += 256) {
      int row = idx / TT, col = idx % TT;
      int ee = min(row0 + row, E - 1);
      sm.ps[row][col] = price_seq[(size_t)ee * TT + col];
    }
    __syncthreads();

    union { uint u[4]; bf16x8 v; } afr[8];
#pragma unroll
    for (int bq = 0; bq < 8; bq++) {
      const float* wr = lWhh + (16 * bq + el) * LH + g * 8;
#pragma unroll
      for (int q = 0; q < 4; q++) {
        float lo = wr[2 * q], hi = wr[2 * q + 1];
        asm("v_cvt_pk_bf16_f32 %0, %1, %2" : "=v"(afr[bq].u[q]) : "v"(lo), "v"(hi));
      }
    }
    uint afr2w[8];
#pragma unroll
    for (int bq = 0; bq < 8; bq++) {
      float wvv = lWih[16 * bq + el];
      float bv = lbih[16 * bq + el] + lbhh[16 * bq + el];
      uint pk;
      asm("v_cvt_pk_bf16_f32 %0, %1, %2" : "=v"(pk) : "v"(wvv), "v"(bv));
      afr2w[bq] = (g == 0) ? pk : 0u;
    }

    int addr_i[4];
#pragma unroll
    for (int i = 0; i < 4; i++) addr_i[i] = (el + 16 * ((g & 1) * 2 + (i >> 1))) << 2;
    bool hi_sel = (g >> 1) != 0;

    float cst[8];
#pragma unroll
    for (int i = 0; i < 8; i++) cst[i] = 0.f;
    uint hpk[4] = {0u, 0u, 0u, 0u};
    const f32x4 zero4 = {0.f, 0.f, 0.f, 0.f};

#pragma unroll 1
    for (int tt = 0; tt < TT; tt++) {
      union { uint u[4]; bf16x8 v; } bfr;
#pragma unroll
      for (int i = 0; i < 4; i++) {
        uint lo = (uint)__builtin_amdgcn_ds_bpermute(addr_i[i], (int)hpk[i & 1]);
        uint hi = (uint)__builtin_amdgcn_ds_bpermute(addr_i[i], (int)hpk[2 + (i & 1)]);
        bfr.u[i] = hi_sel ? hi : lo;
      }
      float x = sm.ps[el_local][tt];
      union { uint u[4]; bf16x8 v; } bfr2;
      uint xp;
      asm("v_cvt_pk_bf16_f32 %0, %1, %2" : "=v"(xp) : "v"(x), "v"(1.0f));
      bfr2.u[0] = (g == 0) ? xp : 0u;
      bfr2.u[1] = 0u; bfr2.u[2] = 0u; bfr2.u[3] = 0u;

      float hval[8];
      f32x4 acc0, acc1, acc2, acc3, acc4, acc5, acc6, acc7;
#define STEPACC(bq, A) \
      { union { uint u[4]; bf16x8 v; } a2; a2.u[0] = afr2w[bq]; a2.u[1] = 0u; a2.u[2] = 0u; a2.u[3] = 0u; \
        A = __builtin_amdgcn_mfma_f32_16x16x32_bf16(a2.v, bfr2.v, zero4, 0, 0, 0); \
        A = __builtin_amdgcn_mfma_f32_16x16x32_bf16(afr[bq].v, bfr.v, A, 0, 0, 0); }
      STEPACC(0, acc0) STEPACC(1, acc1) STEPACC(2, acc2) STEPACC(3, acc3)
      STEPACC(4, acc4) STEPACC(5, acc5) STEPACC(6, acc6) STEPACC(7, acc7)
#undef STEPACC
#define NONLIN(b1q, AI, AF, AG, AO) \
      { _Pragma("unroll") for (int r = 0; r < 4; r++) { \
          int mi = 4 * b1q + r; \
          float ig = sigmoidf_(AI[r]); \
          float fg = sigmoidf_(AF[r]); \
          float gg = tanhfast_(AG[r]); \
          float og = sigmoidf_(AO[r]); \
          float cv = fmaf(fg, cst[mi], ig * gg); \
          cst[mi] = cv; \
          hval[mi] = og * tanhfast_(cv); } }
      NONLIN(0, acc0, acc2, acc4, acc6)
      NONLIN(1, acc1, acc3, acc5, acc7)
#undef NONLIN
#pragma unroll
      for (int i = 0; i < 4; i++)
        asm("v_cvt_pk_bf16_f32 %0, %1, %2" : "=v"(hpk[i]) : "v"(hval[2 * i]), "v"(hval[2 * i + 1]));
    }

    if (valid) {
      uint2* rowp = reinterpret_cast<uint2*>(houtb + (size_t)e * LH);
      rowp[g] = make_uint2(hpk[0], hpk[1]);
      rowp[4 + g] = make_uint2(hpk[2], hpk[3]);
    }
  }
}

// ---------------- K2b: exclusive scan (single block) ----------------
__global__ __launch_bounds__(1024) void scan_kernel(const int* __restrict__ cnt,
                                                    int* __restrict__ offs,
                                                    int* __restrict__ cursor, int N) {
  __shared__ int part[1024];
  int tid = threadIdx.x;
  int chunk = (N + 1023) / 1024;
  int beg = tid * chunk;
  int end = min(beg + chunk, N);
  int s = 0;
  for (int i = beg; i < end; i++) s += cnt[i];
  part[tid] = s;
  __syncthreads();
  for (int d = 1; d < 1024; d <<= 1) {
    int v = (tid >= d) ? part[tid - d] : 0;
    __syncthreads();
    part[tid] += v;
    __syncthreads();
  }
  int run = (tid > 0) ? part[tid - 1] : 0;
  for (int i = beg; i < end; i++) {
    offs[i] = run;
    cursor[i] = run;
    run += cnt[i];
  }
  if (tid == 1023) offs[N] = part[1023];
}

// ---------------- K2c: CSR fill ----------------
__global__ void fill_kernel(const int* __restrict__ src, const int* __restrict__ dst,
                            int* cursor, int* __restrict__ other, int* __restrict__ eid, int E) {
  int e = blockIdx.x * blockDim.x + threadIdx.x;
  if (e >= E) return;
  int s = src[e], d = dst[e];
  int p1 = atomicAdd(&cursor[d], 1);
  other[p1] = s; eid[p1] = e;
  int p2 = atomicAdd(&cursor[s], 1);
  other[p2] = d; eid[p2] = e;
}

// ---- AGG: 16 groups x 32 lanes, 4-deep gather ----
__global__ __launch_bounds__(512) void agg_kernel(
    const int* __restrict__ offs, const int* __restrict__ other, const int* __restrict__ eid,
    const float* __restrict__ mem, const ushort* __restrict__ mem_b,
    const float* __restrict__ msg,
    const float* __restrict__ t, const float* __restrict__ lu,
    const float* __restrict__ tw, const float* __restrict__ tb,
    const int* __restrict__ cnt, ushort* __restrict__ agg_b, int N) {
  __shared__ int ld_oth[256];
  __shared__ int ld_eid[256];
  __shared__ float red[16 * 292];
  int tid = threadIdx.x;
  int grp = tid >> 5;
  int l = tid & 31;
  int v = blockIdx.x;
  int beg = offs[v], end = offs[v + 1];
  int deg = end - beg;
  int ndeg = min(deg, 256);
  for (int i = tid; i < ndeg; i += 512) {
    ld_oth[i] = other[beg + i];
    ld_eid[i] = eid[beg + i];
  }
  __syncthreads();

  float lupd = lu[v];
  float4 w4 = *reinterpret_cast<const float4*>(tw + 4 * l);
  float4 b4 = *reinterpret_cast<const float4*>(tb + 4 * l);
  float a0q0 = 0.f, a0q1 = 0.f, a0q2 = 0.f, a0q3 = 0.f;
  float ac0 = 0.f, ac1 = 0.f, ac2 = 0.f, ac3 = 0.f;
  float amsg = 0.f;
  for (int p0 = grp; p0 < deg; p0 += 64) {
    int uu[4], ee[4];
    float mk[4];
#pragma unroll
    for (int i = 0; i < 4; i++) {
      int p = p0 + 16 * i;
      bool val = (p < deg);
      int ps = val ? p : p0;
      int u, e;
      if (ps < 256) { u = ld_oth[ps]; e = ld_eid[ps]; }
      else { u = other[beg + ps]; e = eid[beg + ps]; }
      uu[i] = u; ee[i] = e; mk[i] = val ? 1.f : 0.f;
    }
    uint2 mr[4];
    float tv[4], mg[4];
#pragma unroll
    for (int i = 0; i < 4; i++) {
      mr[i] = *reinterpret_cast<const uint2*>(mem_b + (size_t)uu[i] * H + 4 * l);
      tv[i] = t[ee[i]];
      mg[i] = msg[ee[i] * EF + l];
    }
#pragma unroll
    for (int i = 0; i < 4; i++) {
      float m = mk[i];
      float x0 = __uint_as_float(mr[i].x << 16);
      float x1 = __uint_as_float(mr[i].x & 0xffff0000u);
      float x2 = __uint_as_float(mr[i].y << 16);
      float x3 = __uint_as_float(mr[i].y & 0xffff0000u);
      a0q0 = fmaf(x0, m, a0q0); a0q1 = fmaf(x1, m, a0q1);
      a0q2 = fmaf(x2, m, a0q2); a0q3 = fmaf(x3, m, a0q3);
      float dt = tv[i] - lupd;
      ac0 = fmaf(__cosf(fmaf(dt, w4.x, b4.x)), m, ac0);
      ac1 = fmaf(__cosf(fmaf(dt, w4.y, b4.y)), m, ac1);
      ac2 = fmaf(__cosf(fmaf(dt, w4.z, b4.z)), m, ac2);
      ac3 = fmaf(__cosf(fmaf(dt, w4.w, b4.w)), m, ac3);
      amsg = fmaf(mg[i], m, amsg);
    }
  }
  float* r = red + grp * 292;
  r[4 * l + 0] = a0q0; r[4 * l + 1] = a0q1; r[4 * l + 2] = a0q2; r[4 * l + 3] = a0q3;
  r[128 + 4 * l + 0] = ac0; r[128 + 4 * l + 1] = ac1;
  r[128 + 4 * l + 2] = ac2; r[128 + 4 * l + 3] = ac3;
  r[256 + l] = amsg;
  __syncthreads();

  int cv = cnt[v];
  float inv = 1.f / (float)max(cv, 1);
  ushort* arow = agg_b + (size_t)v * KTOT;
  if (tid < 288) {
    float s = 0.f;
#pragma unroll
    for (int g2 = 0; g2 < 16; g2++) s += red[g2 * 292 + tid];
    s *= inv;
    if (tid < 128) arow[tid] = f2bf(s);                     // mean neighbor mem
    else if (tid < 256) arow[288 + (tid - 128)] = f2bf(s);  // mean cos
    else arow[256 + (tid - 256)] = f2bf(s);                 // mean msg
  } else if (tid < 416) {
    int c = tid - 288;
    float mv = mem[(size_t)v * H + c];
    arow[128 + c] = f2bf((cv > 0) ? mv : 0.f);  // mean of cv copies of mem[v]
    arow[416 + c] = f2bf(mv);                   // Whh operand
  }
}

// ---- K3: MFMA GEMM + REGISTER-LOCAL GRU finalize -> mem_newb bf16 [N][128] ----
__global__ __launch_bounds__(256) void gru_gemm_mfma(
    const ushort* __restrict__ aggb, const ushort* __restrict__ WcatT,
    const float* __restrict__ mem, const int* __restrict__ cnt,
    const float* __restrict__ bih, const float* __restrict__ bhh,
    ushort* __restrict__ mem_newb, int N) {
  __shared__ ushort As[32 * 552];   // 35.3 KB
  int tid = threadIdx.x;
  int lane = tid & 63;
  int w = tid >> 6;
  int n0 = blockIdx.x * 32;

#pragma unroll
  for (int i = 0; i < 8; i++) {
    int row = w * 8 + i;
    int gr = min(n0 + row, N - 1);
    const uint4* srcp = reinterpret_cast<const uint4*>(aggb + (size_t)gr * KTOT);
    uint4* dstp = reinterpret_cast<uint4*>(As + row * 552);
    dstp[lane] = srcp[lane];
    if (lane < 4) dstp[64 + lane] = srcp[64 + lane];
  }
  __syncthreads();

  f32x4 acc[2][4][2] = {};
  int arow_b = (lane & 15);
  int koff = (lane >> 4) * 8;
  for (int ks = 0; ks < 17; ks++) {
    int k = ks * 32 + koff;
    bf16x8 afr0 = *reinterpret_cast<const bf16x8*>(As + (arow_b) * 552 + k);
    bf16x8 afr1 = *reinterpret_cast<const bf16x8*>(As + (16 + arow_b) * 552 + k);
#pragma unroll
    for (int g = 0; g < 4; g++)
#pragma unroll
      for (int nt = 0; nt < 2; nt++) {
        int o = g * 128 + w * 32 + nt * 16 + (lane & 15);
        bf16x8 bfr = *reinterpret_cast<const bf16x8*>(WcatT + (size_t)o * KTOT + k);
        acc[0][g][nt] = __builtin_amdgcn_mfma_f32_16x16x32_bf16(afr0, bfr, acc[0][g][nt], 0, 0, 0);
        acc[1][g][nt] = __builtin_amdgcn_mfma_f32_16x16x32_bf16(afr1, bfr, acc[1][g][nt], 0, 0, 0);
      }
  }

#pragma unroll
  for (int mt = 0; mt < 2; mt++)
#pragma unroll
    for (int r = 0; r < 4; r++) {
      int n = n0 + mt * 16 + (lane >> 4) * 4 + r;
      if (n >= N) continue;
      int cv = cnt[n];
#pragma unroll
      for (int nt = 0; nt < 2; nt++) {
        int j = w * 32 + nt * 16 + (lane & 15);
        float m = mem[(size_t)n * H + j];
        float o;
        if (cv > 0) {
          float rp = acc[mt][0][nt][r] + bih[j] + bhh[j];
          float zp = acc[mt][1][nt][r] + bih[128 + j] + bhh[128 + j];
          float ip = acc[mt][2][nt][r] + bih[256 + j];
          float hp = acc[mt][3][nt][r] + bhh[256 + j];
          float rr = sigmoidf_(rp), z = sigmoidf_(zp);
          float nn = tanhfast_(ip + rr * hp);
          o = (1.f - z) * nn + z * m;
        } else {
          o = m;
        }
        mem_newb[(size_t)n * H + j] = f2bf(o);
      }
    }
}

// ---------------- K5b: pred bf16 MFMA, 128 edges/block (512 thr, 8 waves) ----------------
__global__ __launch_bounds__(512) void pred_mfma(
    const int* __restrict__ src, const int* __restrict__ dst,
    const int* __restrict__ x_static,
    const ushort* __restrict__ mem_newb, const ushort* __restrict__ houtb,
    const ushort* __restrict__ Wcombb, const float* __restrict__ tab_p,
    const float* __restrict__ tab_s, const float* __restrict__ bias2,
    const float* __restrict__ W2, const float* __restrict__ b2,
    float* __restrict__ out, int E) {
  __shared__ ushort Asm[128 * 296];   // 75.8 KB
  __shared__ int pidx[128], stix[128];
  __shared__ int sidx[128], didx[128];
  int tid = threadIdx.x;
  int row0 = blockIdx.x * 128;
  if (tid < 128) {
    int e = min(row0 + tid, E - 1);
    int s = src[e], d = dst[e];
    sidx[tid] = s; didx[tid] = d;
    pidx[tid] = x_static[s * 2]; stix[tid] = x_static[s * 2 + 1];
  }
  __syncthreads();
#pragma unroll
  for (int i = 0; i < 9; i++) {
    int idx = tid + i * 512;
    int row = idx / 36, c = idx % 36;
    int e = min(row0 + row, E - 1);
    uint4 v;
    if (c < 16) v = reinterpret_cast<const uint4*>(mem_newb + (size_t)sidx[row] * H)[c];
    else if (c < 32) v = reinterpret_cast<const uint4*>(mem_newb + (size_t)didx[row] * H)[c - 16];
    else v = reinterpret_cast<const uint4*>(houtb + (size_t)e * LH)[c - 32];
    *reinterpret_cast<uint4*>(Asm + row * 296 + c * 8) = v;
  }
  __syncthreads();

  int lane = tid & 63;
  int w = tid >> 6;    // 0..7
  f32x4 acc[4] = {};
  int arow = w * 16 + (lane & 15);
  int koff = (lane >> 4) * 8;
  for (int ks = 0; ks < 9; ks++) {
    int k = ks * 32 + koff;
    bf16x8 afr = *reinterpret_cast<const bf16x8*>(Asm + arow * 296 + k);
#pragma unroll
    for (int nt = 0; nt < 4; nt++) {
      int o = nt * 16 + (lane & 15);
      bf16x8 bfr = *reinterpret_cast<const bf16x8*>(Wcombb + (size_t)o * KP + k);
      acc[nt] = __builtin_amdgcn_mfma_f32_16x16x32_bf16(afr, bfr, acc[nt], 0, 0, 0);
    }
  }
  int ocol = lane & 15;
  float bb2 = b2[0];
#pragma unroll
  for (int r = 0; r < 4; r++) {
    int rl = w * 16 + (lane >> 4) * 4 + r;
    int p = pidx[rl], st = stix[rl];
    float s = 0.f;
#pragma unroll
    for (int nt = 0; nt < 4; nt++) {
      int o = nt * 16 + ocol;
      float hv = acc[nt][r] + bias2[o] + tab_p[p * 64 + o] + tab_s[st * 64 + o];
      s = fmaf(fmaxf(hv, 0.f), W2[o], s);
    }
#pragma unroll
    for (int d = 1; d < 16; d <<= 1) s += __shfl_xor(s, d);
    int e = row0 + rl;
    if (ocol == 0 && e < E) out[e] = s + bb2;
  }
}

// ---------------- launch ----------------
extern "C" void kernel_launch(void* const* d_in, const int* in_sizes, int n_in,
                              void* d_out, int out_size, void* d_ws, size_t ws_size,
                              hipStream_t stream) {
  const int* src = (const int*)d_in[0];
  const int* dst = (const int*)d_in[1];
  const float* t = (const float*)d_in[2];
  const float* msg = (const float*)d_in[3];
  const float* price_seq = (const float*)d_in[4];
  const int* x_static = (const int*)d_in[6];
  const float* memory = (const float*)d_in[7];
  const float* last_update = (const float*)d_in[8];
  const float* time_w = (const float*)d_in[9];
  const float* time_b = (const float*)d_in[10];
  const float* gWih = (const float*)d_in[11];
  const float* gWhh = (const float*)d_in[12];
  const float* gbih = (const float*)d_in[13];
  const float* gbhh = (const float*)d_in[14];
  const float* party_emb = (const float*)d_in[15];
  const float* state_emb = (const float*)d_in[16];
  const float* static_W = (const float*)d_in[17];
  const float* static_b = (const float*)d_in[18];
  const float* lWih = (const float*)d_in[19];
  const float* lWhh = (const float*)d_in[20];
  const float* lbih = (const float*)d_in[21];
  const float* lbhh = (const float*)d_in[22];
  const float* price_W = (const float*)d_in[23];
  const float* price_b = (const float*)d_in[24];
  const float* W1 = (const float*)d_in[25];
  const float* b1 = (const float*)d_in[26];
  const float* W2 = (const float*)d_in[27];
  const float* b2 = (const float*)d_in[28];
  float* out = (float*)d_out;

  const int E = in_sizes[0];
  const int N = in_sizes[8];

  char* ws = (char*)d_ws;
  size_t off = 0;
  auto alloc = [&](size_t bytes) { size_t o = off; off += (bytes + 255) & ~(size_t)255; return o; };
  int* cnt       = (int*)(ws + alloc((size_t)N * 4));
  int* offs      = (int*)(ws + alloc((size_t)(N + 1) * 4));
  int* cursor    = (int*)(ws + alloc((size_t)N * 4));
  int* other     = (int*)(ws + alloc((size_t)2 * E * 4));
  int* eid       = (int*)(ws + alloc((size_t)2 * E * 4));
  ushort* WcatT  = (ushort*)(ws + alloc((size_t)GOUT * KTOT * 2));
  ushort* Wcombb = (ushort*)(ws + alloc((size_t)64 * KP * 2));
  float* tab_p   = (float*)(ws + alloc((size_t)4 * 64 * 4));
  float* tab_s   = (float*)(ws + alloc((size_t)50 * 64 * 4));
  float* bias2   = (float*)(ws + alloc((size_t)64 * 4));
  ushort* agg_b  = (ushort*)(ws + alloc((size_t)N * KTOT * 2));
  ushort* mem_newb = (ushort*)(ws + alloc((size_t)N * H * 2));
  ushort* houtb  = (ushort*)(ws + alloc((size_t)E * LH * 2));
  ushort* mem_b  = (ushort*)(ws + alloc((size_t)N * H * 2));
  (void)ws_size;

  hipMemsetAsync(cnt, 0, (size_t)N * 4, stream);

  int nbC = 128, nbN = 128, nbB = (GOUT * KTOT + 255) / 256, nbP = 16;
  int nL = (E + 63) / 64;
  int nbPre = nbC + nbN + nbB + nbP;
  pre_lstm_kernel<<<nbPre + nL, 256, 0, stream>>>(
      gWih, gWhh, WcatT, W1, b1, static_W, static_b, price_W, price_b,
      party_emb, state_emb, Wcombb, tab_p, tab_s, bias2,
      memory, mem_b, src, dst, cnt,
      price_seq, lWih, lWhh, lbih, lbhh, houtb,
      E, N, nbC, nbN, nbB, nbP);
  scan_kernel<<<1, 1024, 0, stream>>>(cnt, offs, cursor, N);
  fill_kernel<<<(E + 255) / 256, 256, 0, stream>>>(src, dst, cursor, other, eid, E);
  agg_kernel<<<N, 512, 0, stream>>>(offs, other, eid, memory, mem_b, msg, t,
                                    last_update, time_w, time_b, cnt, agg_b, N);
  gru_gemm_mfma<<<(N + 31) / 32, 256, 0, stream>>>(agg_b, WcatT, memory, cnt,
                                                   gbih, gbhh, mem_newb, N);
  pred_mfma<<<(E + 127) / 128, 512, 0, stream>>>(src, dst, x_static, mem_newb, houtb,
      Wcombb, tab_p, tab_s, bias2, W2, b2, out, E);
}

// Round 19
// 367.466 us; speedup vs baseline: 1.0072x; 1.0072x over previous
//
#include <hip/hip_runtime.h>

#define H 128
#define EF 32
#define TT 14
#define LH 32
#define KDIM 416   // 3H+EF
#define GOUT 512   // [r_pre, z_pre, i_n, h_n] each 128
#define KTOT 544   // 416 (agg) + 128 (memory)
#define KP 288     // pred GEMM K: 128 ms + 128 md + 32 h

typedef __attribute__((ext_vector_type(8))) short bf16x8;
typedef __attribute__((ext_vector_type(4))) float f32x4;

// native-HW nonlinearities: v_exp_f32 computes 2^x; v_rcp_f32 is ~1ulp.
__device__ __forceinline__ float sigmoidf_(float x) {
  float e = __builtin_amdgcn_exp2f(x * -1.442695041f);   // exp(-x)
  return __builtin_amdgcn_rcpf(1.0f + e);
}
__device__ __forceinline__ float tanhfast_(float x) {
  float e = __builtin_amdgcn_exp2f(x * 2.885390082f);    // exp(2x)
  return 1.0f - 2.0f * __builtin_amdgcn_rcpf(e + 1.0f);
}
__device__ __forceinline__ ushort f2bf(float x) {
  uint u = __float_as_uint(x);
  u += 0x7fff + ((u >> 16) & 1);   // RTNE
  return (ushort)(u >> 16);
}

// ---- FUSED: {mem->bf16 | count | WcatT | prep_pred} block-ranges + LSTM blocks ----
// pre work (~816 light blocks, ~25us of block-time) rides along the 137us lstm long
// pole; agg then runs alone (round-13 showed persistent agg/lstm co-residency hurts).
// Round-16/18 lesson: lstm blocks sit exactly at VGPR=64 (8 waves/SIMD budget) with
// 512-thread blocks — any register increase OR block-size change is an occupancy cliff.
__global__ __launch_bounds__(512) void pre_lstm_kernel(
    const float* __restrict__ gWih, const float* __restrict__ gWhh,
    ushort* __restrict__ WcatT,
    const float* __restrict__ W1, const float* __restrict__ b1,
    const float* __restrict__ static_W, const float* __restrict__ static_b,
    const float* __restrict__ price_W, const float* __restrict__ price_b,
    const float* __restrict__ party_emb, const float* __restrict__ state_emb,
    ushort* __restrict__ Wcombb, float* __restrict__ tab_p, float* __restrict__ tab_s,
    float* __restrict__ bias2,
    const float* __restrict__ mem, ushort* __restrict__ mem_b,
    const int* __restrict__ src, const int* __restrict__ dst, int* cnt,
    const float* __restrict__ price_seq,
    const float* __restrict__ lWih, const float* __restrict__ lWhh,
    const float* __restrict__ lbih, const float* __restrict__ lbhh,
    ushort* __restrict__ houtb,
    int E, int N, int nbC, int nbN, int nbB, int nbP) {
  __shared__ union {
    float ps[128][15];
    float G1s[4][32];
  } sm;
  int b = blockIdx.x;
  int tid = threadIdx.x;
  int nbPre = nbC + nbN + nbB + nbP;

  if (b < nbC) {
    int total = N * H;
    for (int i = tid + 512 * b; i < total; i += 512 * nbC) mem_b[i] = f2bf(mem[i]);
  } else if (b < nbC + nbN) {
    int cb = b - nbC;
    for (int e = tid + 512 * cb; e < E; e += 512 * nbN) {
      atomicAdd(&cnt[dst[e]], 1);
      atomicAdd(&cnt[src[e]], 1);
    }
  } else if (b < nbC + nbN + nbB) {
    int i = (b - nbC - nbN) * 512 + tid;
    if (i < GOUT * KTOT) {
      int o = i / KTOT, k = i % KTOT;
      int j = o & 127;
      float v = 0.f;
      if (o < 256) {
        int row = (o < 128) ? j : (128 + j);
        v = (k < KDIM) ? gWih[row * KDIM + k] : gWhh[row * H + (k - KDIM)];
      } else if (o < 384) {
        v = (k < KDIM) ? gWih[(256 + j) * KDIM + k] : 0.f;
      } else {
        v = (k < KDIM) ? 0.f : gWhh[(256 + j) * H + (k - KDIM)];
      }
      WcatT[i] = f2bf(v);
    }
  } else if (b < nbPre) {
    int ob = (b - nbC - nbN - nbB) * 4;
    if (tid < 128) {
      int ol = tid >> 5, k = tid & 31;
      int o = ob + ol;
      float g = 0.f, m = 0.f;
      for (int j = 0; j < 128; j++) {
        g = fmaf(W1[o * 384 + j], static_W[j * 32 + k], g);
        m = fmaf(W1[o * 384 + 128 + j] + W1[o * 384 + 256 + j], price_W[j * 32 + k], m);
      }
      sm.G1s[ol][k] = g;
      Wcombb[o * KP + 256 + k] = f2bf(m);
    }
    for (int idx = tid; idx < 1024; idx += 512) {
      int ol = idx >> 8, j = idx & 255;
      int o = ob + ol;
      Wcombb[o * KP + j] = f2bf(W1[o * 384 + j]);
    }
    __syncthreads();
    for (int idx = tid; idx < 216; idx += 512) {
      if (idx < 16) {
        int p = idx >> 2, ol = idx & 3;
        float s = 0.f;
        for (int k = 0; k < 16; k++) s = fmaf(sm.G1s[ol][k], party_emb[p * 16 + k], s);
        tab_p[p * 64 + ob + ol] = s;
      } else {
        int i2 = idx - 16;
        int si = i2 >> 2, ol = i2 & 3;
        float s = 0.f;
        for (int k = 0; k < 16; k++) s = fmaf(sm.G1s[ol][16 + k], state_emb[si * 16 + k], s);
        tab_s[si * 64 + ob + ol] = s;
      }
    }
    if (tid < 4) {
      int o = ob + tid;
      float s = b1[o];
      for (int j = 0; j < 128; j++) {
        s = fmaf(W1[o * 384 + j], static_b[j], s);
        s = fmaf(W1[o * 384 + 128 + j] + W1[o * 384 + 256 + j], price_b[j], s);
      }
      bias2[o] = s;
    }
  } else {
    // ================= LSTM path: 8 waves x 16 edges = 128 edges =================
    int lb = b - nbPre;
    int lane = tid & 63;
    int el = lane & 15;
    int g = lane >> 4;
    int wv = tid >> 6;                 // 0..7
    int row0 = lb * 128;
    int el_local = wv * 16 + el;       // 0..127
    int e = row0 + el_local;
    bool valid = (e < E);

    for (int idx = tid; idx < 128 * TT; idx += 512) {
      int row = idx / TT, col = idx % TT;
      int ee = min(row0 + row, E - 1);
      sm.ps[row][col] = price_seq[(size_t)ee * TT + col];
    }
    __syncthreads();

    union { uint u[4]; bf16x8 v; } afr[8];
#pragma unroll
    for (int bq = 0; bq < 8; bq++) {
      const float* wr = lWhh + (16 * bq + el) * LH + g * 8;
#pragma unroll
      for (int q = 0; q < 4; q++) {
        float lo = wr[2 * q], hi = wr[2 * q + 1];
        asm("v_cvt_pk_bf16_f32 %0, %1, %2" : "=v"(afr[bq].u[q]) : "v"(lo), "v"(hi));
      }
    }
    uint afr2w[8];
#pragma unroll
    for (int bq = 0; bq < 8; bq++) {
      float wvv = lWih[16 * bq + el];
      float bv = lbih[16 * bq + el] + lbhh[16 * bq + el];
      uint pk;
      asm("v_cvt_pk_bf16_f32 %0, %1, %2" : "=v"(pk) : "v"(wvv), "v"(bv));
      afr2w[bq] = (g == 0) ? pk : 0u;
    }

    int addr_i[4];
#pragma unroll
    for (int i = 0; i < 4; i++) addr_i[i] = (el + 16 * ((g & 1) * 2 + (i >> 1))) << 2;
    bool hi_sel = (g >> 1) != 0;

    float cst[8];
#pragma unroll
    for (int i = 0; i < 8; i++) cst[i] = 0.f;
    uint hpk[4] = {0u, 0u, 0u, 0u};
    const f32x4 zero4 = {0.f, 0.f, 0.f, 0.f};

#pragma unroll 1
    for (int tt = 0; tt < TT; tt++) {
      union { uint u[4]; bf16x8 v; } bfr;
#pragma unroll
      for (int i = 0; i < 4; i++) {
        uint lo = (uint)__builtin_amdgcn_ds_bpermute(addr_i[i], (int)hpk[i & 1]);
        uint hi = (uint)__builtin_amdgcn_ds_bpermute(addr_i[i], (int)hpk[2 + (i & 1)]);
        bfr.u[i] = hi_sel ? hi : lo;
      }
      float x = sm.ps[el_local][tt];
      union { uint u[4]; bf16x8 v; } bfr2;
      uint xp;
      asm("v_cvt_pk_bf16_f32 %0, %1, %2" : "=v"(xp) : "v"(x), "v"(1.0f));
      bfr2.u[0] = (g == 0) ? xp : 0u;
      bfr2.u[1] = 0u; bfr2.u[2] = 0u; bfr2.u[3] = 0u;

      float hval[8];
      f32x4 acc0, acc1, acc2, acc3, acc4, acc5, acc6, acc7;
#define STEPACC(bq, A) \
      { union { uint u[4]; bf16x8 v; } a2; a2.u[0] = afr2w[bq]; a2.u[1] = 0u; a2.u[2] = 0u; a2.u[3] = 0u; \
        A = __builtin_amdgcn_mfma_f32_16x16x32_bf16(a2.v, bfr2.v, zero4, 0, 0, 0); \
        A = __builtin_amdgcn_mfma_f32_16x16x32_bf16(afr[bq].v, bfr.v, A, 0, 0, 0); }
      STEPACC(0, acc0) STEPACC(1, acc1) STEPACC(2, acc2) STEPACC(3, acc3)
      STEPACC(4, acc4) STEPACC(5, acc5) STEPACC(6, acc6) STEPACC(7, acc7)
#undef STEPACC
#define NONLIN(b1q, AI, AF, AG, AO) \
      { _Pragma("unroll") for (int r = 0; r < 4; r++) { \
          int mi = 4 * b1q + r; \
          float ig = sigmoidf_(AI[r]); \
          float fg = sigmoidf_(AF[r]); \
          float gg = tanhfast_(AG[r]); \
          float og = sigmoidf_(AO[r]); \
          float cv = fmaf(fg, cst[mi], ig * gg); \
          cst[mi] = cv; \
          hval[mi] = og * tanhfast_(cv); } }
      NONLIN(0, acc0, acc2, acc4, acc6)
      NONLIN(1, acc1, acc3, acc5, acc7)
#undef NONLIN
#pragma unroll
      for (int i = 0; i < 4; i++)
        asm("v_cvt_pk_bf16_f32 %0, %1, %2" : "=v"(hpk[i]) : "v"(hval[2 * i]), "v"(hval[2 * i + 1]));
    }

    if (valid) {
      uint2* rowp = reinterpret_cast<uint2*>(houtb + (size_t)e * LH);
      rowp[g] = make_uint2(hpk[0], hpk[1]);
      rowp[4 + g] = make_uint2(hpk[2], hpk[3]);
    }
  }
}

// ---------------- K2b: exclusive scan (single block) ----------------
__global__ __launch_bounds__(1024) void scan_kernel(const int* __restrict__ cnt,
                                                    int* __restrict__ offs,
                                                    int* __restrict__ cursor, int N) {
  __shared__ int part[1024];
  int tid = threadIdx.x;
  int chunk = (N + 1023) / 1024;
  int beg = tid * chunk;
  int end = min(beg + chunk, N);
  int s = 0;
  for (int i = beg; i < end; i++) s += cnt[i];
  part[tid] = s;
  __syncthreads();
  for (int d = 1; d < 1024; d <<= 1) {
    int v = (tid >= d) ? part[tid - d] : 0;
    __syncthreads();
    part[tid] += v;
    __syncthreads();
  }
  int run = (tid > 0) ? part[tid - 1] : 0;
  for (int i = beg; i < end; i++) {
    offs[i] = run;
    cursor[i] = run;
    run += cnt[i];
  }
  if (tid == 1023) offs[N] = part[1023];
}

// ---------------- K2c: CSR fill ----------------
__global__ void fill_kernel(const int* __restrict__ src, const int* __restrict__ dst,
                            int* cursor, int* __restrict__ other, int* __restrict__ eid, int E) {
  int e = blockIdx.x * blockDim.x + threadIdx.x;
  if (e >= E) return;
  int s = src[e], d = dst[e];
  int p1 = atomicAdd(&cursor[d], 1);
  other[p1] = s; eid[p1] = e;
  int p2 = atomicAdd(&cursor[s], 1);
  other[p2] = d; eid[p2] = e;
}

// ---- AGG: 16 groups x 32 lanes, 4-deep gather ----
__global__ __launch_bounds__(512) void agg_kernel(
    const int* __restrict__ offs, const int* __restrict__ other, const int* __restrict__ eid,
    const float* __restrict__ mem, const ushort* __restrict__ mem_b,
    const float* __restrict__ msg,
    const float* __restrict__ t, const float* __restrict__ lu,
    const float* __restrict__ tw, const float* __restrict__ tb,
    const int* __restrict__ cnt, ushort* __restrict__ agg_b, int N) {
  __shared__ int ld_oth[256];
  __shared__ int ld_eid[256];
  __shared__ float red[16 * 292];
  int tid = threadIdx.x;
  int grp = tid >> 5;
  int l = tid & 31;
  int v = blockIdx.x;
  int beg = offs[v], end = offs[v + 1];
  int deg = end - beg;
  int ndeg = min(deg, 256);
  for (int i = tid; i < ndeg; i += 512) {
    ld_oth[i] = other[beg + i];
    ld_eid[i] = eid[beg + i];
  }
  __syncthreads();

  float lupd = lu[v];
  float4 w4 = *reinterpret_cast<const float4*>(tw + 4 * l);
  float4 b4 = *reinterpret_cast<const float4*>(tb + 4 * l);
  float a0q0 = 0.f, a0q1 = 0.f, a0q2 = 0.f, a0q3 = 0.f;
  float ac0 = 0.f, ac1 = 0.f, ac2 = 0.f, ac3 = 0.f;
  float amsg = 0.f;
  for (int p0 = grp; p0 < deg; p0 += 64) {
    int uu[4], ee[4];
    float mk[4];
#pragma unroll
    for (int i = 0; i < 4; i++) {
      int p = p0 + 16 * i;
      bool val = (p < deg);
      int ps = val ? p : p0;
      int u, e;
      if (ps < 256) { u = ld_oth[ps]; e = ld_eid[ps]; }
      else { u = other[beg + ps]; e = eid[beg + ps]; }
      uu[i] = u; ee[i] = e; mk[i] = val ? 1.f : 0.f;
    }
    uint2 mr[4];
    float tv[4], mg[4];
#pragma unroll
    for (int i = 0; i < 4; i++) {
      mr[i] = *reinterpret_cast<const uint2*>(mem_b + (size_t)uu[i] * H + 4 * l);
      tv[i] = t[ee[i]];
      mg[i] = msg[ee[i] * EF + l];
    }
#pragma unroll
    for (int i = 0; i < 4; i++) {
      float m = mk[i];
      float x0 = __uint_as_float(mr[i].x << 16);
      float x1 = __uint_as_float(mr[i].x & 0xffff0000u);
      float x2 = __uint_as_float(mr[i].y << 16);
      float x3 = __uint_as_float(mr[i].y & 0xffff0000u);
      a0q0 = fmaf(x0, m, a0q0); a0q1 = fmaf(x1, m, a0q1);
      a0q2 = fmaf(x2, m, a0q2); a0q3 = fmaf(x3, m, a0q3);
      float dt = tv[i] - lupd;
      ac0 = fmaf(__cosf(fmaf(dt, w4.x, b4.x)), m, ac0);
      ac1 = fmaf(__cosf(fmaf(dt, w4.y, b4.y)), m, ac1);
      ac2 = fmaf(__cosf(fmaf(dt, w4.z, b4.z)), m, ac2);
      ac3 = fmaf(__cosf(fmaf(dt, w4.w, b4.w)), m, ac3);
      amsg = fmaf(mg[i], m, amsg);
    }
  }
  float* r = red + grp * 292;
  r[4 * l + 0] = a0q0; r[4 * l + 1] = a0q1; r[4 * l + 2] = a0q2; r[4 * l + 3] = a0q3;
  r[128 + 4 * l + 0] = ac0; r[128 + 4 * l + 1] = ac1;
  r[128 + 4 * l + 2] = ac2; r[128 + 4 * l + 3] = ac3;
  r[256 + l] = amsg;
  __syncthreads();

  int cv = cnt[v];
  float inv = 1.f / (float)max(cv, 1);
  ushort* arow = agg_b + (size_t)v * KTOT;
  if (tid < 288) {
    float s = 0.f;
#pragma unroll
    for (int g2 = 0; g2 < 16; g2++) s += red[g2 * 292 + tid];
    s *= inv;
    if (tid < 128) arow[tid] = f2bf(s);                     // mean neighbor mem
    else if (tid < 256) arow[288 + (tid - 128)] = f2bf(s);  // mean cos
    else arow[256 + (tid - 256)] = f2bf(s);                 // mean msg
  } else if (tid < 416) {
    int c = tid - 288;
    float mv = mem[(size_t)v * H + c];
    arow[128 + c] = f2bf((cv > 0) ? mv : 0.f);  // mean of cv copies of mem[v]
    arow[416 + c] = f2bf(mv);                   // Whh operand
  }
}

// ---- K3: MFMA GEMM + REGISTER-LOCAL GRU finalize -> mem_newb bf16 [N][128] ----
__global__ __launch_bounds__(256) void gru_gemm_mfma(
    const ushort* __restrict__ aggb, const ushort* __restrict__ WcatT,
    const float* __restrict__ mem, const int* __restrict__ cnt,
    const float* __restrict__ bih, const float* __restrict__ bhh,
    ushort* __restrict__ mem_newb, int N) {
  __shared__ ushort As[32 * 552];   // 35.3 KB
  int tid = threadIdx.x;
  int lane = tid & 63;
  int w = tid >> 6;
  int n0 = blockIdx.x * 32;

#pragma unroll
  for (int i = 0; i < 8; i++) {
    int row = w * 8 + i;
    int gr = min(n0 + row, N - 1);
    const uint4* srcp = reinterpret_cast<const uint4*>(aggb + (size_t)gr * KTOT);
    uint4* dstp = reinterpret_cast<uint4*>(As + row * 552);
    dstp[lane] = srcp[lane];
    if (lane < 4) dstp[64 + lane] = srcp[64 + lane];
  }
  __syncthreads();

  f32x4 acc[2][4][2] = {};
  int arow_b = (lane & 15);
  int koff = (lane >> 4) * 8;
  for (int ks = 0; ks < 17; ks++) {
    int k = ks * 32 + koff;
    bf16x8 afr0 = *reinterpret_cast<const bf16x8*>(As + (arow_b) * 552 + k);
    bf16x8 afr1 = *reinterpret_cast<const bf16x8*>(As + (16 + arow_b) * 552 + k);
#pragma unroll
    for (int g = 0; g < 4; g++)
#pragma unroll
      for (int nt = 0; nt < 2; nt++) {
        int o = g * 128 + w * 32 + nt * 16 + (lane & 15);
        bf16x8 bfr = *reinterpret_cast<const bf16x8*>(WcatT + (size_t)o * KTOT + k);
        acc[0][g][nt] = __builtin_amdgcn_mfma_f32_16x16x32_bf16(afr0, bfr, acc[0][g][nt], 0, 0, 0);
        acc[1][g][nt] = __builtin_amdgcn_mfma_f32_16x16x32_bf16(afr1, bfr, acc[1][g][nt], 0, 0, 0);
      }
  }

#pragma unroll
  for (int mt = 0; mt < 2; mt++)
#pragma unroll
    for (int r = 0; r < 4; r++) {
      int n = n0 + mt * 16 + (lane >> 4) * 4 + r;
      if (n >= N) continue;
      int cv = cnt[n];
#pragma unroll
      for (int nt = 0; nt < 2; nt++) {
        int j = w * 32 + nt * 16 + (lane & 15);
        float m = mem[(size_t)n * H + j];
        float o;
        if (cv > 0) {
          float rp = acc[mt][0][nt][r] + bih[j] + bhh[j];
          float zp = acc[mt][1][nt][r] + bih[128 + j] + bhh[128 + j];
          float ip = acc[mt][2][nt][r] + bih[256 + j];
          float hp = acc[mt][3][nt][r] + bhh[256 + j];
          float rr = sigmoidf_(rp), z = sigmoidf_(zp);
          float nn = tanhfast_(ip + rr * hp);
          o = (1.f - z) * nn + z * m;
        } else {
          o = m;
        }
        mem_newb[(size_t)n * H + j] = f2bf(o);
      }
    }
}

// ---------------- K5b: pred bf16 MFMA, 128 edges/block (512 thr, 8 waves) ----------------
__global__ __launch_bounds__(512) void pred_mfma(
    const int* __restrict__ src, const int* __restrict__ dst,
    const int* __restrict__ x_static,
    const ushort* __restrict__ mem_newb, const ushort* __restrict__ houtb,
    const ushort* __restrict__ Wcombb, const float* __restrict__ tab_p,
    const float* __restrict__ tab_s, const float* __restrict__ bias2,
    const float* __restrict__ W2, const float* __restrict__ b2,
    float* __restrict__ out, int E) {
  __shared__ ushort Asm[128 * 296];   // 75.8 KB
  __shared__ int pidx[128], stix[128];
  __shared__ int sidx[128], didx[128];
  int tid = threadIdx.x;
  int row0 = blockIdx.x * 128;
  if (tid < 128) {
    int e = min(row0 + tid, E - 1);
    int s = src[e], d = dst[e];
    sidx[tid] = s; didx[tid] = d;
    pidx[tid] = x_static[s * 2]; stix[tid] = x_static[s * 2 + 1];
  }
  __syncthreads();
#pragma unroll
  for (int i = 0; i < 9; i++) {
    int idx = tid + i * 512;
    int row = idx / 36, c = idx % 36;
    int e = min(row0 + row, E - 1);
    uint4 v;
    if (c < 16) v = reinterpret_cast<const uint4*>(mem_newb + (size_t)sidx[row] * H)[c];
    else if (c < 32) v = reinterpret_cast<const uint4*>(mem_newb + (size_t)didx[row] * H)[c - 16];
    else v = reinterpret_cast<const uint4*>(houtb + (size_t)e * LH)[c - 32];
    *reinterpret_cast<uint4*>(Asm + row * 296 + c * 8) = v;
  }
  __syncthreads();

  int lane = tid & 63;
  int w = tid >> 6;    // 0..7
  f32x4 acc[4] = {};
  int arow = w * 16 + (lane & 15);
  int koff = (lane >> 4) * 8;
  for (int ks = 0; ks < 9; ks++) {
    int k = ks * 32 + koff;
    bf16x8 afr = *reinterpret_cast<const bf16x8*>(Asm + arow * 296 + k);
#pragma unroll
    for (int nt = 0; nt < 4; nt++) {
      int o = nt * 16 + (lane & 15);
      bf16x8 bfr = *reinterpret_cast<const bf16x8*>(Wcombb + (size_t)o * KP + k);
      acc[nt] = __builtin_amdgcn_mfma_f32_16x16x32_bf16(afr, bfr, acc[nt], 0, 0, 0);
    }
  }
  int ocol = lane & 15;
  float bb2 = b2[0];
#pragma unroll
  for (int r = 0; r < 4; r++) {
    int rl = w * 16 + (lane >> 4) * 4 + r;
    int p = pidx[rl], st = stix[rl];
    float s = 0.f;
#pragma unroll
    for (int nt = 0; nt < 4; nt++) {
      int o = nt * 16 + ocol;
      float hv = acc[nt][r] + bias2[o] + tab_p[p * 64 + o] + tab_s[st * 64 + o];
      s = fmaf(fmaxf(hv, 0.f), W2[o], s);
    }
#pragma unroll
    for (int d = 1; d < 16; d <<= 1) s += __shfl_xor(s, d);
    int e = row0 + rl;
    if (ocol == 0 && e < E) out[e] = s + bb2;
  }
}

// ---------------- launch ----------------
extern "C" void kernel_launch(void* const* d_in, const int* in_sizes, int n_in,
                              void* d_out, int out_size, void* d_ws, size_t ws_size,
                              hipStream_t stream) {
  const int* src = (const int*)d_in[0];
  const int* dst = (const int*)d_in[1];
  const float* t = (const float*)d_in[2];
  const float* msg = (const float*)d_in[3];
  const float* price_seq = (const float*)d_in[4];
  const int* x_static = (const int*)d_in[6];
  const float* memory = (const float*)d_in[7];
  const float* last_update = (const float*)d_in[8];
  const float* time_w = (const float*)d_in[9];
  const float* time_b = (const float*)d_in[10];
  const float* gWih = (const float*)d_in[11];
  const float* gWhh = (const float*)d_in[12];
  const float* gbih = (const float*)d_in[13];
  const float* gbhh = (const float*)d_in[14];
  const float* party_emb = (const float*)d_in[15];
  const float* state_emb = (const float*)d_in[16];
  const float* static_W = (const float*)d_in[17];
  const float* static_b = (const float*)d_in[18];
  const float* lWih = (const float*)d_in[19];
  const float* lWhh = (const float*)d_in[20];
  const float* lbih = (const float*)d_in[21];
  const float* lbhh = (const float*)d_in[22];
  const float* price_W = (const float*)d_in[23];
  const float* price_b = (const float*)d_in[24];
  const float* W1 = (const float*)d_in[25];
  const float* b1 = (const float*)d_in[26];
  const float* W2 = (const float*)d_in[27];
  const float* b2 = (const float*)d_in[28];
  float* out = (float*)d_out;

  const int E = in_sizes[0];
  const int N = in_sizes[8];

  char* ws = (char*)d_ws;
  size_t off = 0;
  auto alloc = [&](size_t bytes) { size_t o = off; off += (bytes + 255) & ~(size_t)255; return o; };
  int* cnt       = (int*)(ws + alloc((size_t)N * 4));
  int* offs      = (int*)(ws + alloc((size_t)(N + 1) * 4));
  int* cursor    = (int*)(ws + alloc((size_t)N * 4));
  int* other     = (int*)(ws + alloc((size_t)2 * E * 4));
  int* eid       = (int*)(ws + alloc((size_t)2 * E * 4));
  ushort* WcatT  = (ushort*)(ws + alloc((size_t)GOUT * KTOT * 2));
  ushort* Wcombb = (ushort*)(ws + alloc((size_t)64 * KP * 2));
  float* tab_p   = (float*)(ws + alloc((size_t)4 * 64 * 4));
  float* tab_s   = (float*)(ws + alloc((size_t)50 * 64 * 4));
  float* bias2   = (float*)(ws + alloc((size_t)64 * 4));
  ushort* agg_b  = (ushort*)(ws + alloc((size_t)N * KTOT * 2));
  ushort* mem_newb = (ushort*)(ws + alloc((size_t)N * H * 2));
  ushort* houtb  = (ushort*)(ws + alloc((size_t)E * LH * 2));
  ushort* mem_b  = (ushort*)(ws + alloc((size_t)N * H * 2));
  (void)ws_size;

  hipMemsetAsync(cnt, 0, (size_t)N * 4, stream);

  int nbC = 128, nbN = 128, nbB = (GOUT * KTOT + 511) / 512, nbP = 16;
  int nL = (E + 127) / 128;
  int nbPre = nbC + nbN + nbB + nbP;
  pre_lstm_kernel<<<nbPre + nL, 512, 0, stream>>>(
      gWih, gWhh, WcatT, W1, b1, static_W, static_b, price_W, price_b,
      party_emb, state_emb, Wcombb, tab_p, tab_s, bias2,
      memory, mem_b, src, dst, cnt,
      price_seq, lWih, lWhh, lbih, lbhh, houtb,
      E, N, nbC, nbN, nbB, nbP);
  scan_kernel<<<1, 1024, 0, stream>>>(cnt, offs, cursor, N);
  fill_kernel<<<(E + 255) / 256, 256, 0, stream>>>(src, dst, cursor, other, eid, E);
  agg_kernel<<<N, 512, 0, stream>>>(offs, other, eid, memory, mem_b, msg, t,
                                    last_update, time_w, time_b, cnt, agg_b, N);
  gru_gemm_mfma<<<(N + 31) / 32, 256, 0, stream>>>(agg_b, WcatT, memory, cnt,
                                                   gbih, gbhh, mem_newb, N);
  pred_mfma<<<(E + 127) / 128, 512, 0, stream>>>(src, dst, x_static, mem_newb, houtb,
      Wcombb, tab_p, tab_s, bias2, W2, b2, out, E);
}